// Round 6
// baseline (1159.970 us; speedup 1.0000x reference)
//
#include <hip/hip_runtime.h>
#include <math.h>

#define EPS 1e-5f

constexpr int NCH  = 59;
constexpr int T_   = 300;
constexpr int WIN  = 5;
constexpr int WSIZE= 100;
constexpr int Bb   = 64;
constexpr int NB   = Bb*WIN;     // 320
constexpr int NN   = Bb*NCH;     // 3776
constexpr int EW_N = 216;
constexpr int NE   = EW_N*Bb;    // 13824
constexpr int C1   = 20;
constexpr int C13  = 10;
constexpr int F150 = 150;
constexpr int F100 = 100;
constexpr int HID  = 256;
constexpr int GATES= 1024;
constexpr int NROW = NB*NCH;     // 18880
constexpr float CNT1  = 1888000.0f;   // NB*NCH*WSIZE
constexpr float CNT13 = 2832000.0f;   // NB*NCH*F150

__device__ __forceinline__ float leaky(float v){ return v >= 0.f ? v : 0.01f*v; }
__device__ __forceinline__ float sigm(float v){ return 1.f/(1.f+expf(-v)); }

__global__ __launch_bounds__(256)
void zero_kernel(float* __restrict__ p, int n)
{
    int i = blockIdx.x*256 + threadIdx.x;
    if (i < n) p[i] = 0.f;
}

// ---------------------------------------------------------------------------
// 1-D conv (unchanged from round 4): one (b,hh) row/block, SGPR weights.
// ---------------------------------------------------------------------------
template<int KW, int PAD, int CIDX, int APPLY>
__global__ __launch_bounds__(256)
void conv1d_kernel(const float* __restrict__ x, const float* __restrict__ wt_g,
                   const float* __restrict__ sclall, const float* __restrict__ sftall,
                   const float* __restrict__ w13,
                   float* __restrict__ stats1, float* __restrict__ stats13,
                   float* __restrict__ y13)
{
    __shared__ float xp[WIN*240];
    __shared__ float lstat[2*C1];

    const int row = blockIdx.x;            // b*NCH + hh
    const int b   = row / NCH, hh = row - b*NCH;
    const int tid = threadIdx.x;
    const float* xrow = x + (size_t)row*T_;

    for (int i = tid; i < WIN*240; i += 256){
        int win = i/240, ii = i - win*240;
        int t = ii - PAD;
        xp[i] = (t >= 0 && t < WSIZE) ? xrow[win*50 + t] : 0.f;
    }
    if (tid < 2*C1) lstat[tid] = 0.f;
    __syncthreads();

    const bool active = (tid < 250);
    const int win = tid / 50, u = tid - win*50;

    float a0[C1], a1[C1];
    #pragma unroll
    for (int c = 0; c < C1; c++){ a0[c] = 0.f; a1[c] = 0.f; }

    if (active){
        const float* xw = &xp[win*240 + 2*u];
        float xa = xw[0];
        #pragma unroll 2
        for (int k = 0; k < KW; k++){
            float xb = xw[k+1];
            #pragma unroll
            for (int c = 0; c < C1; c++){
                float wv = wt_g[c*KW + k];      // wave-uniform -> s_load
                a0[c] += wv*xa;
                a1[c] += wv*xb;
            }
            xa = xb;
        }
    }

    if (!APPLY){
        #pragma unroll
        for (int c = 0; c < C1; c++){
            float s = a0[c] + a1[c];
            float q = a0[c]*a0[c] + a1[c]*a1[c];
            for (int off = 32; off; off >>= 1){
                s += __shfl_down(s, off, 64);
                q += __shfl_down(q, off, 64);
            }
            if ((tid & 63) == 0){
                atomicAdd(&lstat[c],      s);
                atomicAdd(&lstat[C1 + c], q);
            }
        }
        __syncthreads();
        const int st = row & 63;
        if (tid < 2*C1) atomicAdd(&stats1[st*120 + CIDX*40 + tid], lstat[tid]);
    } else {
        float y[C13];
        if (active){
            float pooled[C1];
            #pragma unroll
            for (int c = 0; c < C1; c++){
                float sc = sclall[CIDX*C1 + c];
                float sf = sftall[CIDX*C1 + c];
                pooled[c] = 0.5f*(leaky(a0[c]*sc + sf) + leaky(a1[c]*sc + sf));
            }
            #pragma unroll
            for (int o = 0; o < C13; o++){
                float acc = 0.f;
                #pragma unroll
                for (int c = 0; c < C1; c++) acc += w13[o*C1 + c]*pooled[c];
                y[o] = acc;                       // b13 cancels in BN13
            }
            const int n = b*WIN + win;
            #pragma unroll
            for (int o = 0; o < C13; o++)
                y13[(((size_t)n*C13 + o)*NCH + hh)*F150 + CIDX*50 + u] = y[o];
        } else {
            #pragma unroll
            for (int o = 0; o < C13; o++) y[o] = 0.f;
        }
        #pragma unroll
        for (int o = 0; o < C13; o++){
            float s = y[o], q = y[o]*y[o];
            for (int off = 32; off; off >>= 1){
                s += __shfl_down(s, off, 64);
                q += __shfl_down(q, off, 64);
            }
            if ((tid & 63) == 0){
                atomicAdd(&lstat[o],       s);
                atomicAdd(&lstat[C13 + o], q);
            }
        }
        __syncthreads();
        const int st = row & 63;
        if (tid < 2*C13) atomicAdd(&stats13[st*(2*C13) + tid], lstat[tid]);
    }
}

__global__ void finalize_bn1(const float* __restrict__ stats1,
                             const float* __restrict__ g1, const float* __restrict__ be1,
                             const float* __restrict__ g2, const float* __restrict__ be2,
                             const float* __restrict__ g3, const float* __restrict__ be3,
                             float* __restrict__ sclall, float* __restrict__ sftall)
{
    int idx = threadIdx.x;
    if (idx >= 60) return;
    int conv = idx/20, c = idx - conv*20;
    float s=0.f, q=0.f;
    for (int st=0; st<64; st++){
        s += stats1[st*120 + conv*40 + c];
        q += stats1[st*120 + conv*40 + 20 + c];
    }
    float m = s/CNT1, v = q/CNT1 - m*m;
    float rs = rsqrtf(v + EPS);
    const float* g  = conv==0 ? g1  : (conv==1 ? g2  : g3);
    const float* be = conv==0 ? be1 : (conv==1 ? be2 : be3);
    sclall[idx] = rs*g[c];
    sftall[idx] = be[c] - m*rs*g[c];
}

__global__ void finalize_bn13(const float* __restrict__ stats13,
                              const float* __restrict__ g13, const float* __restrict__ be13,
                              float* __restrict__ scl13, float* __restrict__ sft13)
{
    int o = threadIdx.x;
    if (o >= C13) return;
    float s=0.f, q=0.f;
    for (int st=0; st<64; st++){
        s += stats13[st*20 + o];
        q += stats13[st*20 + C13 + o];
    }
    float m = s/CNT13, v = q/CNT13 - m*m;
    float rs = rsqrtf(v + EPS);
    scl13[o] = rs*g13[o];
    sft13[o] = be13[o] - m*rs*g13[o];
}

__global__ __launch_bounds__(256)
void feat_kernel(const float* __restrict__ y13,
                 const float* __restrict__ scl13, const float* __restrict__ sft13,
                 float* __restrict__ feat)
{
    __shared__ float scl[C13], sft[C13];
    int blk = blockIdx.x;
    int n = blk / NCH, hh = blk - n*NCH;
    int b = n / WIN, win = n - b*WIN;
    int tid = threadIdx.x;
    if (tid < C13){ scl[tid] = scl13[tid]; sft[tid] = sft13[tid]; }
    __syncthreads();
    float* fr = feat + ((size_t)(b*NCH+hh)*WIN + win)*F150;
    for (int f = tid; f < F150; f += 256){
        float acc = 0.f;
        #pragma unroll
        for (int o = 0; o < C13; o++){
            float v = y13[((size_t)(n*C13+o)*NCH+hh)*F150 + f];
            acc += leaky(v*scl[o] + sft[o]);
        }
        fr[f] = acc;
    }
}

__global__ __launch_bounds__(256)
void gcn_h_kernel(const float* __restrict__ feat, const float* __restrict__ gw,
                  float* __restrict__ h)
{
    __shared__ float fr[8*F150];
    int r0 = blockIdx.x*8;
    int tid = threadIdx.x;
    for (int i = tid; i < 8*F150; i += 256) fr[i] = feat[(size_t)r0*F150 + i];
    __syncthreads();
    for (int idx = tid; idx < 8*F100; idx += 256){
        int rr = idx / F100, j = idx - rr*F100;
        float acc = 0.f;
        const float* f = &fr[rr*F150];
        for (int k = 0; k < F150; k++) acc += f[k]*gw[k*F100 + j];
        h[(size_t)(r0+rr)*F100 + j] = acc;
    }
}

__global__ void deg_kernel(const int* __restrict__ ei, const float* __restrict__ ew,
                           float* __restrict__ deg)
{
    int e = blockIdx.x*blockDim.x + threadIdx.x;
    if (e >= NE) return;
    int c = ei[NE + e];
    float w = ew[e % EW_N]; w = w > 0.f ? w : 0.f;
    atomicAdd(&deg[c], w);
}

__global__ void dinv_kernel(float* __restrict__ deg)
{
    int i = blockIdx.x*blockDim.x + threadIdx.x;
    if (i < NN) deg[i] = rsqrtf(deg[i] + 1.0f);
}

__global__ __launch_bounds__(64)
void agg_kernel(const int* __restrict__ ei, const float* __restrict__ ew,
                const float* __restrict__ dinv, const float* __restrict__ h,
                float* __restrict__ agg)
{
    int e = blockIdx.x;
    int r = ei[e], c = ei[NE + e];
    float w = ew[e % EW_N]; w = w > 0.f ? w : 0.f;
    float nrm = dinv[r]*w*dinv[c];
    const float* hr = h + (size_t)r*(WIN*F100);
    float* ac = agg + (size_t)c*(WIN*F100);
    for (int i = threadIdx.x; i < WIN*F100; i += 64)
        atomicAdd(&ac[i], hr[i]*nrm);
}

__global__ __launch_bounds__(256)
void bn2_stats_kernel(const float* __restrict__ h, const float* __restrict__ dinv,
                      float* __restrict__ agg, float* __restrict__ s2sum, float* __restrict__ s2sq)
{
    int tid = threadIdx.x;
    int c0 = tid, c1 = tid + 256;
    float s0=0.f,q0=0.f,s1=0.f,q1=0.f;
    for (int rr = 0; rr < NCH; rr++){
        int node = blockIdx.x*NCH + rr;
        float d = dinv[node]; float d2 = d*d;
        const float* hr = h + (size_t)node*(WIN*F100);
        float* ar = agg + (size_t)node*(WIN*F100);
        float v0 = ar[c0] + hr[c0]*d2;
        ar[c0] = v0; s0 += v0; q0 += v0*v0;
        if (c1 < WIN*F100){
            float v1 = ar[c1] + hr[c1]*d2;
            ar[c1] = v1; s1 += v1; q1 += v1*v1;
        }
    }
    atomicAdd(&s2sum[c0], s0); atomicAdd(&s2sq[c0], q0);
    if (c1 < WIN*F100){ atomicAdd(&s2sum[c1], s1); atomicAdd(&s2sq[c1], q1); }
}

__global__ void bn2_fin_kernel(const float* __restrict__ s2sum, const float* __restrict__ s2sq,
                               const float* __restrict__ g2, const float* __restrict__ b2,
                               float* __restrict__ scl2, float* __restrict__ sft2)
{
    int c = blockIdx.x*blockDim.x + threadIdx.x;
    if (c >= WIN*F100) return;
    int f = c % F100;
    float m = s2sum[c]/(float)NN;
    float v = s2sq[c]/(float)NN - m*m;
    float rs = rsqrtf(v + EPS);
    scl2[c] = rs*g2[f];
    sft2[c] = b2[f] - m*rs*g2[f];
}

__global__ __launch_bounds__(256)
void zconv_kernel(const float* __restrict__ agg,
                  const float* __restrict__ scl2, const float* __restrict__ sft2,
                  const float* __restrict__ w11, const float* __restrict__ b11,
                  float* __restrict__ seq)
{
    __shared__ float z[NCH*WSIZE];
    __shared__ float ws[C13*NCH*2];
    __shared__ float sc[WSIZE], sf[WSIZE];
    int n = blockIdx.x;
    int b = n / WIN, win = n - b*WIN;
    int tid = threadIdx.x;
    if (tid < WSIZE){ sc[tid] = scl2[win*F100 + tid]; sf[tid] = sft2[win*F100 + tid]; }
    for (int i = tid; i < C13*NCH*2; i += 256) ws[i] = w11[i];
    __syncthreads();
    for (int i = tid; i < NCH*WSIZE; i += 256){
        int ch = i / WSIZE, t = i - ch*WSIZE;
        int node = b*NCH + ch;
        float v = agg[(size_t)node*(WIN*F100) + win*F100 + t];
        z[i] = v*sc[t] + sf[t];
    }
    __syncthreads();
    float* sq = seq + (size_t)n*490;
    for (int idx = tid; idx < C13*49; idx += 256){
        int o = idx / 49, p = idx - o*49;
        float ve = b11[o], vo = b11[o];
        const float* wo = &ws[o*NCH*2];
        for (int ch = 0; ch < NCH; ch++){
            float z0 = z[ch*WSIZE + 2*p];
            float z1 = z[ch*WSIZE + 2*p + 1];
            float z2 = z[ch*WSIZE + 2*p + 2];
            float w0 = wo[ch*2], w1 = wo[ch*2 + 1];
            ve += w0*z0 + w1*z1;
            vo += w0*z1 + w1*z2;
        }
        sq[o*49 + p] = 0.5f*(leaky(ve) + leaky(vo));
    }
}

__global__ void transpose_kernel(const float* __restrict__ src, float* __restrict__ dst, int R, int C)
{
    int idx = blockIdx.x*blockDim.x + threadIdx.x;
    if (idx >= R*C) return;
    int r = idx % R, c = idx / R;
    dst[idx] = src[(size_t)r*C + c];
}

// ---------------------------------------------------------------------------
// LSTM, step-wise batched. xg0 = seq @ wih0T^T + (bih0+bhh0)  (320 x 1024)
// grid: 20 row-tiles x 8 j-tiles; 512 threads: 16 rows x 32 j-quads.
// ---------------------------------------------------------------------------
__global__ __launch_bounds__(512)
void xgates_kernel(const float* __restrict__ seq, const float* __restrict__ wT,
                   const float* __restrict__ bih, const float* __restrict__ bhh,
                   float* __restrict__ xg)
{
    __shared__ float xs[16*490];
    const int rt = blockIdx.x >> 3, jt_tile = blockIdx.x & 7;
    const int r0 = rt*16, jc = jt_tile*128;
    const int tid = threadIdx.x;
    for (int i = tid; i < 16*490; i += 512)
        xs[i] = seq[(size_t)(r0 + i/490)*490 + (i - (i/490)*490)];
    __syncthreads();
    const int bl = tid >> 5, jq = tid & 31;
    const int j = jc + jq*4;
    const float* xrow = &xs[bl*490];
    float4 acc;
    {
        float4 b1v = *(const float4*)&bih[j];
        float4 b2v = *(const float4*)&bhh[j];
        acc.x = b1v.x+b2v.x; acc.y = b1v.y+b2v.y; acc.z = b1v.z+b2v.z; acc.w = b1v.w+b2v.w;
    }
    const float* wp = wT + j;
    #pragma unroll 5
    for (int k = 0; k < 490; k++){
        float xv = xrow[k];
        float4 w = *(const float4*)&wp[(size_t)k*GATES];
        acc.x += w.x*xv; acc.y += w.y*xv; acc.z += w.z*xv; acc.w += w.w*xv;
    }
    *(float4*)&xg[(size_t)(r0 + bl)*GATES + j] = acc;
}

// layer-0 step: gates = xg0[:,t,:] + h_in @ whh0T; cell update; h_out, out1[:,t,:]
// grid: 32 = 4 b-tiles x 8 m-tiles; 512 threads = 16 b x (4 gates x 8 m-quads)
__global__ __launch_bounds__(512)
void lstm_step0(const float* __restrict__ xg0, const float* __restrict__ whhT,
                const float* __restrict__ hin, float* __restrict__ hout,
                float* __restrict__ cst, float* __restrict__ out1, int t)
{
    __shared__ float xs[16*HID];
    __shared__ float lg[4*16*32];
    const int bt = blockIdx.x & 3, mt = blockIdx.x >> 2;
    const int b0 = bt*16, m0 = mt*32;
    const int tid = threadIdx.x;
    for (int i = tid; i < 16*HID; i += 512)
        xs[i] = hin[(size_t)(b0 + (i>>8))*HID + (i&255)];
    __syncthreads();
    const int bl = tid >> 5, jq = tid & 31;
    const int g = jq >> 3, ms = (jq&7)*4;
    const int j = g*HID + m0 + ms;
    const float* xrow = &xs[bl*HID];
    float4 acc = *(const float4*)&xg0[((size_t)(b0+bl)*WIN + t)*GATES + j];
    const float* wp = whhT + j;
    #pragma unroll 8
    for (int k = 0; k < HID; k++){
        float xv = xrow[k];
        float4 w = *(const float4*)&wp[(size_t)k*GATES];
        acc.x += w.x*xv; acc.y += w.y*xv; acc.z += w.z*xv; acc.w += w.w*xv;
    }
    *(float4*)&lg[(g*16 + bl)*32 + ms] = acc;
    __syncthreads();
    const int ib = tid >> 5, im = tid & 31;
    {
        float gi = lg[(0*16+ib)*32+im], gf = lg[(1*16+ib)*32+im];
        float gg = lg[(2*16+ib)*32+im], go = lg[(3*16+ib)*32+im];
        const int gb = b0 + ib, gm = m0 + im;
        float c = cst[(size_t)gb*HID + gm];
        c = sigm(gf)*c + sigm(gi)*tanhf(gg);
        float h = sigm(go)*tanhf(c);
        cst[(size_t)gb*HID + gm] = c;
        hout[(size_t)gb*HID + gm] = h;
        out1[((size_t)gb*WIN + t)*HID + gm] = h;
    }
}

// layer-1 step: gates = bb1 + out1[:,t,:] @ wih1T + h_in @ whh1T
__global__ __launch_bounds__(512)
void lstm_step1(const float* __restrict__ out1,
                const float* __restrict__ wihT, const float* __restrict__ whhT,
                const float* __restrict__ bih, const float* __restrict__ bhh,
                const float* __restrict__ hin, float* __restrict__ hout,
                float* __restrict__ cst, float* __restrict__ out2, int t)
{
    __shared__ float xs1[16*HID];
    __shared__ float xs2[16*HID];
    __shared__ float lg[4*16*32];
    const int bt = blockIdx.x & 3, mt = blockIdx.x >> 2;
    const int b0 = bt*16, m0 = mt*32;
    const int tid = threadIdx.x;
    for (int i = tid; i < 16*HID; i += 512){
        xs1[i] = out1[((size_t)(b0 + (i>>8))*WIN + t)*HID + (i&255)];
        xs2[i] = hin[(size_t)(b0 + (i>>8))*HID + (i&255)];
    }
    __syncthreads();
    const int bl = tid >> 5, jq = tid & 31;
    const int g = jq >> 3, ms = (jq&7)*4;
    const int j = g*HID + m0 + ms;
    float4 acc;
    {
        float4 b1v = *(const float4*)&bih[j];
        float4 b2v = *(const float4*)&bhh[j];
        acc.x = b1v.x+b2v.x; acc.y = b1v.y+b2v.y; acc.z = b1v.z+b2v.z; acc.w = b1v.w+b2v.w;
    }
    const float* xrow1 = &xs1[bl*HID];
    const float* wp1 = wihT + j;
    #pragma unroll 8
    for (int k = 0; k < HID; k++){
        float xv = xrow1[k];
        float4 w = *(const float4*)&wp1[(size_t)k*GATES];
        acc.x += w.x*xv; acc.y += w.y*xv; acc.z += w.z*xv; acc.w += w.w*xv;
    }
    const float* xrow2 = &xs2[bl*HID];
    const float* wp2 = whhT + j;
    #pragma unroll 8
    for (int k = 0; k < HID; k++){
        float xv = xrow2[k];
        float4 w = *(const float4*)&wp2[(size_t)k*GATES];
        acc.x += w.x*xv; acc.y += w.y*xv; acc.z += w.z*xv; acc.w += w.w*xv;
    }
    *(float4*)&lg[(g*16 + bl)*32 + ms] = acc;
    __syncthreads();
    const int ib = tid >> 5, im = tid & 31;
    {
        float gi = lg[(0*16+ib)*32+im], gf = lg[(1*16+ib)*32+im];
        float gg = lg[(2*16+ib)*32+im], go = lg[(3*16+ib)*32+im];
        const int gb = b0 + ib, gm = m0 + im;
        float c = cst[(size_t)gb*HID + gm];
        c = sigm(gf)*c + sigm(gi)*tanhf(gg);
        float h = sigm(go)*tanhf(c);
        cst[(size_t)gb*HID + gm] = c;
        hout[(size_t)gb*HID + gm] = h;
        out2[((size_t)gb*WIN + t)*HID + gm] = h;
    }
}

// attention over out2 (b, t, 256): softmax_t(dot(out2[b,t], out2[b,4])) -> weighted sum
__global__ __launch_bounds__(256)
void attn_kernel(const float* __restrict__ out2, float* __restrict__ out)
{
    __shared__ float red[5*4];
    __shared__ float aw[5];
    const int b = blockIdx.x, tid = threadIdx.x;
    const float hl = out2[((size_t)b*WIN + 4)*HID + tid];
    const int wave = tid >> 6, lane = tid & 63;
    float v[5];
    #pragma unroll
    for (int t = 0; t < 5; t++){
        v[t] = out2[((size_t)b*WIN + t)*HID + tid];
        float p = v[t]*hl;
        for (int off = 32; off > 0; off >>= 1) p += __shfl_down(p, off);
        if (lane == 0) red[t*4 + wave] = p;
    }
    __syncthreads();
    if (tid == 0){
        float s[5], mx = -1e30f;
        for (int t = 0; t < 5; t++){ s[t] = red[t*4]+red[t*4+1]+red[t*4+2]+red[t*4+3]; mx = fmaxf(mx, s[t]); }
        float den = 0.f;
        for (int t = 0; t < 5; t++){ s[t] = expf(s[t]-mx); den += s[t]; }
        for (int t = 0; t < 5; t++) aw[t] = s[t]/den;
    }
    __syncthreads();
    float o = 0.f;
    #pragma unroll
    for (int t = 0; t < 5; t++) o += aw[t]*v[t];
    out[(size_t)b*HID + tid] = o;
}

extern "C" void kernel_launch(void* const* d_in, const int* in_sizes, int n_in,
                              void* d_out, int out_size, void* d_ws, size_t ws_size,
                              hipStream_t stream)
{
    const float* x     = (const float*)d_in[0];
    const float* w1    = (const float*)d_in[1];
    const float* g1    = (const float*)d_in[3];
    const float* be1   = (const float*)d_in[4];
    const float* w2    = (const float*)d_in[5];
    const float* g2    = (const float*)d_in[7];
    const float* be2   = (const float*)d_in[8];
    const float* w3    = (const float*)d_in[9];
    const float* g3    = (const float*)d_in[11];
    const float* be3   = (const float*)d_in[12];
    const float* w13   = (const float*)d_in[13];
    const float* g13   = (const float*)d_in[15];
    const float* be13  = (const float*)d_in[16];
    const float* gcn_w = (const float*)d_in[17];
    const float* edge_w= (const float*)d_in[19];
    const float* bn2g  = (const float*)d_in[20];
    const float* bn2b  = (const float*)d_in[21];
    const float* w11   = (const float*)d_in[22];
    const float* b11   = (const float*)d_in[23];
    const float* wih0  = (const float*)d_in[24];
    const float* whh0  = (const float*)d_in[25];
    const float* bih0  = (const float*)d_in[26];
    const float* bhh0  = (const float*)d_in[27];
    const float* wih1  = (const float*)d_in[28];
    const float* whh1  = (const float*)d_in[29];
    const float* bih1  = (const float*)d_in[30];
    const float* bhh1  = (const float*)d_in[31];
    const int*   ei    = (const int*)d_in[32];
    float* out = (float*)d_out;
    float* wsf = (float*)d_ws;
    (void)in_sizes; (void)n_in; (void)out_size; (void)ws_size;

    size_t off = 0;
    auto alloc = [&](size_t n){ size_t o = off; off += (n + 63) & ~(size_t)63; return o; };
    size_t Y13  = alloc((size_t)NB*C13*NCH*F150);    // 113 MB
    size_t FEAT = alloc((size_t)NN*WIN*F150);
    size_t HB   = alloc((size_t)NN*WIN*F100);
    size_t AGG  = alloc((size_t)NN*WIN*F100);        // [zeroed from here]
    size_t DEG  = alloc(NN);
    size_t ST1  = alloc(64*120);
    size_t ST13 = alloc(64*20);
    size_t BN2S = alloc(1000);
    size_t H0A  = alloc(Bb*HID);
    size_t H0B  = alloc(Bb*HID);
    size_t H1A  = alloc(Bb*HID);
    size_t H1B  = alloc(Bb*HID);
    size_t CS0  = alloc(Bb*HID);
    size_t CS1  = alloc(Bb*HID);
    size_t SCLA = alloc(64);                         // [zero region ends here]
    size_t SFTA = alloc(64);
    size_t SC13 = alloc(16);
    size_t SF13 = alloc(16);
    size_t SCL2 = alloc(1024);
    size_t WT0I = alloc((size_t)490*1024);
    size_t WT0H = alloc((size_t)256*1024);
    size_t WT1I = alloc((size_t)256*1024);
    size_t WT1H = alloc((size_t)256*1024);
    size_t SEQ  = alloc((size_t)Bb*WIN*490);
    size_t XG0  = alloc((size_t)NB*GATES);
    size_t OUT1 = alloc((size_t)NB*HID);
    size_t OUT2 = alloc((size_t)NB*HID);

    float* y13   = wsf + Y13;
    float* feat  = wsf + FEAT;
    float* hbuf  = wsf + HB;
    float* agg   = wsf + AGG;
    float* dinv  = wsf + DEG;
    float* st1   = wsf + ST1;
    float* st13  = wsf + ST13;
    float* bn2s  = wsf + BN2S;
    float* h0a   = wsf + H0A;
    float* h0b   = wsf + H0B;
    float* h1a   = wsf + H1A;
    float* h1b   = wsf + H1B;
    float* cs0   = wsf + CS0;
    float* cs1   = wsf + CS1;
    float* sclA  = wsf + SCLA;
    float* sftA  = wsf + SFTA;
    float* sc13  = wsf + SC13;
    float* sf13  = wsf + SF13;
    float* scl2  = wsf + SCL2;
    float* wT0i  = wsf + WT0I;
    float* wT0h  = wsf + WT0H;
    float* wT1i  = wsf + WT1I;
    float* wT1h  = wsf + WT1H;
    float* seqb  = wsf + SEQ;
    float* xg0   = wsf + XG0;
    float* out1b = wsf + OUT1;
    float* out2b = wsf + OUT2;

    int nzero = (int)(SCLA - AGG);
    zero_kernel<<<(nzero+255)/256,256,0,stream>>>(wsf + AGG, nzero);

    {
        int n0 = 1024*490;
        transpose_kernel<<<(n0+255)/256,256,0,stream>>>(wih0, wT0i, 1024, 490);
        int n1 = 1024*256;
        transpose_kernel<<<(n1+255)/256,256,0,stream>>>(whh0, wT0h, 1024, 256);
        transpose_kernel<<<(n1+255)/256,256,0,stream>>>(wih1, wT1i, 1024, 256);
        transpose_kernel<<<(n1+255)/256,256,0,stream>>>(whh1, wT1h, 1024, 256);
    }

    // pass A: stats
    conv1d_kernel<125,62,0,0><<<NN,256,0,stream>>>(x, w1, sclA, sftA, w13, st1, st13, y13);
    conv1d_kernel< 59,29,1,0><<<NN,256,0,stream>>>(x, w2, sclA, sftA, w13, st1, st13, y13);
    conv1d_kernel< 31,15,2,0><<<NN,256,0,stream>>>(x, w3, sclA, sftA, w13, st1, st13, y13);
    finalize_bn1<<<1,64,0,stream>>>(st1, g1, be1, g2, be2, g3, be3, sclA, sftA);
    // pass B: apply + mix
    conv1d_kernel<125,62,0,1><<<NN,256,0,stream>>>(x, w1, sclA, sftA, w13, st1, st13, y13);
    conv1d_kernel< 59,29,1,1><<<NN,256,0,stream>>>(x, w2, sclA, sftA, w13, st1, st13, y13);
    conv1d_kernel< 31,15,2,1><<<NN,256,0,stream>>>(x, w3, sclA, sftA, w13, st1, st13, y13);
    finalize_bn13<<<1,16,0,stream>>>(st13, g13, be13, sc13, sf13);

    feat_kernel<<<NROW,256,0,stream>>>(y13, sc13, sf13, feat);
    gcn_h_kernel<<<NROW/8,256,0,stream>>>(feat, gcn_w, hbuf);

    deg_kernel<<<(NE+255)/256,256,0,stream>>>(ei, edge_w, dinv);
    dinv_kernel<<<(NN+255)/256,256,0,stream>>>(dinv);
    agg_kernel<<<NE,64,0,stream>>>(ei, edge_w, dinv, hbuf, agg);
    bn2_stats_kernel<<<Bb,256,0,stream>>>(hbuf, dinv, agg, bn2s, bn2s+500);
    bn2_fin_kernel<<<2,256,0,stream>>>(bn2s, bn2s+500, bn2g, bn2b, scl2, scl2+500);

    zconv_kernel<<<NB,256,0,stream>>>(agg, scl2, scl2+500, w11, b11, seqb);

    // LSTM pipeline
    xgates_kernel<<<160,512,0,stream>>>(seqb, wT0i, bih0, bhh0, xg0);
    for (int t = 0; t < WIN; t++){
        float* h0in  = (t & 1) ? h0b : h0a;
        float* h0out = (t & 1) ? h0a : h0b;
        float* h1in  = (t & 1) ? h1b : h1a;
        float* h1out = (t & 1) ? h1a : h1b;
        lstm_step0<<<32,512,0,stream>>>(xg0, wT0h, h0in, h0out, cs0, out1b, t);
        lstm_step1<<<32,512,0,stream>>>(out1b, wT1i, wT1h, bih1, bhh1,
                                        h1in, h1out, cs1, out2b, t);
    }
    attn_kernel<<<Bb,256,0,stream>>>(out2b, out);
}

// Round 8
// 885.503 us; speedup vs baseline: 1.3100x; 1.3100x over previous
//
#include <hip/hip_runtime.h>
#include <math.h>

#define EPS 1e-5f

constexpr int NCH  = 59;
constexpr int T_   = 300;
constexpr int WIN  = 5;
constexpr int WSIZE= 100;
constexpr int Bb   = 64;
constexpr int NB   = Bb*WIN;     // 320
constexpr int NN   = Bb*NCH;     // 3776
constexpr int EW_N = 216;
constexpr int NE   = EW_N*Bb;    // 13824
constexpr int C1   = 20;
constexpr int C13  = 10;
constexpr int F150 = 150;
constexpr int F100 = 100;
constexpr int HID  = 256;
constexpr int GATES= 1024;
constexpr int NROW = NB*NCH;     // 18880
constexpr int NWIN = NROW;       // 18880 (row,win) windows
constexpr float CNT1  = 1888000.0f;   // NB*NCH*WSIZE
constexpr float CNT13 = 2832000.0f;   // NB*NCH*F150

__device__ __forceinline__ float leaky(float v){ return v >= 0.f ? v : 0.01f*v; }
__device__ __forceinline__ float sigm(float v){ return 1.f/(1.f+expf(-v)); }

__global__ __launch_bounds__(256)
void zero_kernel(float* __restrict__ p, int n)
{
    int i = blockIdx.x*256 + threadIdx.x;
    if (i < n) p[i] = 0.f;
}

// ---------------------------------------------------------------------------
// Gram-stats path: M = X^T X over all 18880 windows (X row = 100 samples),
// V = column sums. Then Q_d[t] = prefix over diagonal d of M, R = prefix of V.
// BN1 stats follow algebraically from (Q,R) -- replaces the 16.2 GFLOP
// stats conv pass with a 0.38 GFLOP syrk.
// ---------------------------------------------------------------------------
__global__ __launch_bounds__(256)
void syrk_kernel(const float* __restrict__ x, float* __restrict__ M, float* __restrict__ V)
{
    __shared__ float xs[128*100 + 16];     // +pad: tile reads may run 11 past end
    const int k0 = blockIdx.x * 128;
    const int tid = threadIdx.x;
    for (int i = tid; i < 128*100; i += 256){
        int wl = i / 100, u = i - wl*100;
        int w = k0 + wl;
        float v = 0.f;
        if (w < NWIN){
            int row = w / 5, win = w - row*5;
            v = x[(size_t)row*T_ + win*50 + u];
        }
        xs[i] = v;
    }
    if (tid < 16) xs[128*100 + tid] = 0.f;
    __syncthreads();
    if (tid < 100){
        float s = 0.f;
        for (int kk = 0; kk < 128; kk++) s += xs[kk*100 + tid];
        atomicAdd(&V[tid], s);
    }
    const int i = tid >> 4, j = tid & 15;
    float acc[7][7];
    #pragma unroll
    for (int a=0;a<7;a++)
        #pragma unroll
        for (int b=0;b<7;b++) acc[a][b]=0.f;
    for (int kk = 0; kk < 128; kk++){
        const float* xr = &xs[kk*100];
        float xu[7], xv[7];
        #pragma unroll
        for (int a=0;a<7;a++) xu[a] = xr[a*16 + i];
        #pragma unroll
        for (int b=0;b<7;b++) xv[b] = xr[b*16 + j];
        #pragma unroll
        for (int a=0;a<7;a++)
            #pragma unroll
            for (int b=0;b<7;b++) acc[a][b] += xu[a]*xv[b];
    }
    #pragma unroll
    for (int a=0;a<7;a++){
        int u = a*16 + i;
        if (u < 100){
            #pragma unroll
            for (int b=0;b<7;b++){
                int v = b*16 + j;
                if (v < 100) atomicAdd(&M[u*100 + v], acc[a][b]);
            }
        }
    }
}

__global__ void qprep_kernel(const float* __restrict__ M, const float* __restrict__ V,
                             float* __restrict__ Q, float* __restrict__ R)
{
    int d = threadIdx.x;
    if (d < 100){
        float s = 0.f;
        Q[d*101] = 0.f;
        for (int t = 1; t <= 100; t++){
            int u = t - 1;
            if (u + d < 100) s += M[u*100 + u + d];
            Q[d*101 + t] = s;
        }
    } else if (d == 100){
        float s = 0.f;
        R[0] = 0.f;
        for (int t = 1; t <= 100; t++){ s += V[t-1]; R[t] = s; }
    }
}

// one block per (conv, channel): contract w x w against G (via Q) -> scl/sft
__global__ __launch_bounds__(256)
void gram_finalize(const float* __restrict__ Q, const float* __restrict__ Rg,
                   const float* __restrict__ w1, const float* __restrict__ w2, const float* __restrict__ w3,
                   const float* __restrict__ g1, const float* __restrict__ be1,
                   const float* __restrict__ g2, const float* __restrict__ be2,
                   const float* __restrict__ g3, const float* __restrict__ be3,
                   float* __restrict__ sclall, float* __restrict__ sftall)
{
    __shared__ float Qs[100*101];
    __shared__ float ws[128];
    __shared__ float Rs[104];
    __shared__ float red[8];
    const int conv = blockIdx.x / 20, c = blockIdx.x - conv*20;
    const int KW  = conv==0 ? 125 : (conv==1 ? 59 : 31);
    const int PAD = (KW-1)/2;
    const float* wt = conv==0 ? w1 : (conv==1 ? w2 : w3);
    const int tid = threadIdx.x;
    for (int i = tid; i < 100*101; i += 256) Qs[i] = Q[i];
    for (int i = tid; i < KW; i += 256) ws[i] = wt[c*KW + i];
    if (tid < 101) Rs[tid] = Rg[tid];
    __syncthreads();
    const int DMAX = KW < 100 ? KW : 100;
    float sq = 0.f;
    for (int d = 0; d < DMAX; d++){
        float fac = (d == 0) ? 1.f : 2.f;
        for (int k1 = tid; k1 < KW - d; k1 += 256){
            int lo = k1 - PAD; if (lo < 0) lo = 0;
            int hi = 100 - d; int h2 = 100 + k1 - PAD; if (h2 < hi) hi = h2;
            if (hi > lo) sq += fac * ws[k1]*ws[k1+d] * (Qs[d*101 + hi] - Qs[d*101 + lo]);
        }
    }
    float sm = 0.f;
    for (int k = tid; k < KW; k += 256){
        int lo = k - PAD; if (lo < 0) lo = 0;
        int hi = 100; int h2 = k - PAD + 100; if (h2 < hi) hi = h2;
        if (hi > lo) sm += ws[k]*(Rs[hi] - Rs[lo]);
    }
    for (int off = 32; off; off >>= 1){
        sq += __shfl_down(sq, off, 64);
        sm += __shfl_down(sm, off, 64);
    }
    int wave = tid >> 6, lane = tid & 63;
    if (lane == 0){ red[wave] = sq; red[4+wave] = sm; }
    __syncthreads();
    if (tid == 0){
        float q = (red[0]+red[1]+red[2]+red[3]) / CNT1;
        float m = (red[4]+red[5]+red[6]+red[7]) / CNT1;
        float var = q - m*m;
        float rs = rsqrtf(var + EPS);
        const float* g  = conv==0 ? g1  : (conv==1 ? g2  : g3);
        const float* be = conv==0 ? be1 : (conv==1 ? be2 : be3);
        sclall[conv*C1 + c] = rs*g[c];
        sftall[conv*C1 + c] = be[c] - m*rs*g[c];
    }
}

// ---------------------------------------------------------------------------
// 1-D conv apply pass (round-4 structure, unroll 4): one (b,hh) row per block.
// ---------------------------------------------------------------------------
template<int KW, int PAD, int CIDX>
__global__ __launch_bounds__(256)
void conv1d_apply(const float* __restrict__ x, const float* __restrict__ wt_g,
                  const float* __restrict__ sclall, const float* __restrict__ sftall,
                  const float* __restrict__ w13,
                  float* __restrict__ stats13, float* __restrict__ y13)
{
    __shared__ float xp[WIN*240];
    __shared__ float lstat[2*C13];

    const int row = blockIdx.x;
    const int b   = row / NCH, hh = row - b*NCH;
    const int tid = threadIdx.x;
    const float* xrow = x + (size_t)row*T_;

    for (int i = tid; i < WIN*240; i += 256){
        int win = i/240, ii = i - win*240;
        int t = ii - PAD;
        xp[i] = (t >= 0 && t < WSIZE) ? xrow[win*50 + t] : 0.f;
    }
    if (tid < 2*C13) lstat[tid] = 0.f;
    __syncthreads();

    const bool active = (tid < 250);
    const int win = tid / 50, u = tid - win*50;

    float a0[C1], a1[C1];
    #pragma unroll
    for (int c = 0; c < C1; c++){ a0[c] = 0.f; a1[c] = 0.f; }

    if (active){
        const float* xw = &xp[win*240 + 2*u];
        float xa = xw[0];
        #pragma unroll 4
        for (int k = 0; k < KW; k++){
            float xb = xw[k+1];
            #pragma unroll
            for (int c = 0; c < C1; c++){
                float wv = wt_g[c*KW + k];      // wave-uniform -> s_load
                a0[c] += wv*xa;
                a1[c] += wv*xb;
            }
            xa = xb;
        }
    }

    float y[C13];
    if (active){
        float pooled[C1];
        #pragma unroll
        for (int c = 0; c < C1; c++){
            float sc = sclall[CIDX*C1 + c];
            float sf = sftall[CIDX*C1 + c];
            pooled[c] = 0.5f*(leaky(a0[c]*sc + sf) + leaky(a1[c]*sc + sf));
        }
        #pragma unroll
        for (int o = 0; o < C13; o++){
            float acc = 0.f;
            #pragma unroll
            for (int c = 0; c < C1; c++) acc += w13[o*C1 + c]*pooled[c];
            y[o] = acc;                       // b13 cancels in BN13
        }
        const int n = b*WIN + win;
        #pragma unroll
        for (int o = 0; o < C13; o++)
            y13[(((size_t)n*C13 + o)*NCH + hh)*F150 + CIDX*50 + u] = y[o];
    } else {
        #pragma unroll
        for (int o = 0; o < C13; o++) y[o] = 0.f;
    }
    #pragma unroll
    for (int o = 0; o < C13; o++){
        float s = y[o], q = y[o]*y[o];
        for (int off = 32; off; off >>= 1){
            s += __shfl_down(s, off, 64);
            q += __shfl_down(q, off, 64);
        }
        if ((tid & 63) == 0){
            atomicAdd(&lstat[o],       s);
            atomicAdd(&lstat[C13 + o], q);
        }
    }
    __syncthreads();
    const int st = row & 63;
    if (tid < 2*C13) atomicAdd(&stats13[st*(2*C13) + tid], lstat[tid]);
}

__global__ void finalize_bn13(const float* __restrict__ stats13,
                              const float* __restrict__ g13, const float* __restrict__ be13,
                              float* __restrict__ scl13, float* __restrict__ sft13)
{
    int o = threadIdx.x;
    if (o >= C13) return;
    float s=0.f, q=0.f;
    for (int st=0; st<64; st++){
        s += stats13[st*20 + o];
        q += stats13[st*20 + C13 + o];
    }
    float m = s/CNT13, v = q/CNT13 - m*m;
    float rs = rsqrtf(v + EPS);
    scl13[o] = rs*g13[o];
    sft13[o] = be13[o] - m*rs*g13[o];
}

__global__ __launch_bounds__(256)
void feat_kernel(const float* __restrict__ y13,
                 const float* __restrict__ scl13, const float* __restrict__ sft13,
                 float* __restrict__ feat)
{
    __shared__ float scl[C13], sft[C13];
    int blk = blockIdx.x;
    int n = blk / NCH, hh = blk - n*NCH;
    int b = n / WIN, win = n - b*WIN;
    int tid = threadIdx.x;
    if (tid < C13){ scl[tid] = scl13[tid]; sft[tid] = sft13[tid]; }
    __syncthreads();
    float* fr = feat + ((size_t)(b*NCH+hh)*WIN + win)*F150;
    for (int f = tid; f < F150; f += 256){
        float acc = 0.f;
        #pragma unroll
        for (int o = 0; o < C13; o++){
            float v = y13[((size_t)(n*C13+o)*NCH+hh)*F150 + f];
            acc += leaky(v*scl[o] + sft[o]);
        }
        fr[f] = acc;
    }
}

__global__ __launch_bounds__(256)
void gcn_h_kernel(const float* __restrict__ feat, const float* __restrict__ gw,
                  float* __restrict__ h)
{
    __shared__ float fr[8*F150];
    int r0 = blockIdx.x*8;
    int tid = threadIdx.x;
    for (int i = tid; i < 8*F150; i += 256) fr[i] = feat[(size_t)r0*F150 + i];
    __syncthreads();
    for (int idx = tid; idx < 8*F100; idx += 256){
        int rr = idx / F100, j = idx - rr*F100;
        float acc = 0.f;
        const float* f = &fr[rr*F150];
        for (int k = 0; k < F150; k++) acc += f[k]*gw[k*F100 + j];
        h[(size_t)(r0+rr)*F100 + j] = acc;
    }
}

__global__ void deg_kernel(const int* __restrict__ ei, const float* __restrict__ ew,
                           float* __restrict__ deg)
{
    int e = blockIdx.x*blockDim.x + threadIdx.x;
    if (e >= NE) return;
    int c = ei[NE + e];
    float w = ew[e % EW_N]; w = w > 0.f ? w : 0.f;
    atomicAdd(&deg[c], w);
}

__global__ void dinv_kernel(float* __restrict__ deg)
{
    int i = blockIdx.x*blockDim.x + threadIdx.x;
    if (i < NN) deg[i] = rsqrtf(deg[i] + 1.0f);
}

__global__ __launch_bounds__(64)
void agg_kernel(const int* __restrict__ ei, const float* __restrict__ ew,
                const float* __restrict__ dinv, const float* __restrict__ h,
                float* __restrict__ agg)
{
    int e = blockIdx.x;
    int r = ei[e], c = ei[NE + e];
    float w = ew[e % EW_N]; w = w > 0.f ? w : 0.f;
    float nrm = dinv[r]*w*dinv[c];
    const float* hr = h + (size_t)r*(WIN*F100);
    float* ac = agg + (size_t)c*(WIN*F100);
    for (int i = threadIdx.x; i < WIN*F100; i += 64)
        atomicAdd(&ac[i], hr[i]*nrm);
}

__global__ __launch_bounds__(256)
void bn2_stats_kernel(const float* __restrict__ h, const float* __restrict__ dinv,
                      float* __restrict__ agg, float* __restrict__ s2sum, float* __restrict__ s2sq)
{
    int tid = threadIdx.x;
    int c0 = tid, c1 = tid + 256;
    float s0=0.f,q0=0.f,s1=0.f,q1=0.f;
    for (int rr = 0; rr < NCH; rr++){
        int node = blockIdx.x*NCH + rr;
        float d = dinv[node]; float d2 = d*d;
        const float* hr = h + (size_t)node*(WIN*F100);
        float* ar = agg + (size_t)node*(WIN*F100);
        float v0 = ar[c0] + hr[c0]*d2;
        ar[c0] = v0; s0 += v0; q0 += v0*v0;
        if (c1 < WIN*F100){
            float v1 = ar[c1] + hr[c1]*d2;
            ar[c1] = v1; s1 += v1; q1 += v1*v1;
        }
    }
    atomicAdd(&s2sum[c0], s0); atomicAdd(&s2sq[c0], q0);
    if (c1 < WIN*F100){ atomicAdd(&s2sum[c1], s1); atomicAdd(&s2sq[c1], q1); }
}

__global__ void bn2_fin_kernel(const float* __restrict__ s2sum, const float* __restrict__ s2sq,
                               const float* __restrict__ g2, const float* __restrict__ b2,
                               float* __restrict__ scl2, float* __restrict__ sft2)
{
    int c = blockIdx.x*blockDim.x + threadIdx.x;
    if (c >= WIN*F100) return;
    int f = c % F100;
    float m = s2sum[c]/(float)NN;
    float v = s2sq[c]/(float)NN - m*m;
    float rs = rsqrtf(v + EPS);
    scl2[c] = rs*g2[f];
    sft2[c] = b2[f] - m*rs*g2[f];
}

__global__ __launch_bounds__(256)
void zconv_kernel(const float* __restrict__ agg,
                  const float* __restrict__ scl2, const float* __restrict__ sft2,
                  const float* __restrict__ w11, const float* __restrict__ b11,
                  float* __restrict__ seq)
{
    __shared__ float z[NCH*WSIZE];
    __shared__ float ws[C13*NCH*2];
    __shared__ float sc[WSIZE], sf[WSIZE];
    int n = blockIdx.x;
    int b = n / WIN, win = n - b*WIN;
    int tid = threadIdx.x;
    if (tid < WSIZE){ sc[tid] = scl2[win*F100 + tid]; sf[tid] = sft2[win*F100 + tid]; }
    for (int i = tid; i < C13*NCH*2; i += 256) ws[i] = w11[i];
    __syncthreads();
    for (int i = tid; i < NCH*WSIZE; i += 256){
        int ch = i / WSIZE, t = i - ch*WSIZE;
        int node = b*NCH + ch;
        float v = agg[(size_t)node*(WIN*F100) + win*F100 + t];
        z[i] = v*sc[t] + sf[t];
    }
    __syncthreads();
    float* sq = seq + (size_t)n*490;
    for (int idx = tid; idx < C13*49; idx += 256){
        int o = idx / 49, p = idx - o*49;
        float ve = b11[o], vo = b11[o];
        const float* wo = &ws[o*NCH*2];
        for (int ch = 0; ch < NCH; ch++){
            float z0 = z[ch*WSIZE + 2*p];
            float z1 = z[ch*WSIZE + 2*p + 1];
            float z2 = z[ch*WSIZE + 2*p + 2];
            float w0 = wo[ch*2], w1 = wo[ch*2 + 1];
            ve += w0*z0 + w1*z1;
            vo += w0*z1 + w1*z2;
        }
        sq[o*49 + p] = 0.5f*(leaky(ve) + leaky(vo));
    }
}

__global__ void transpose_kernel(const float* __restrict__ src, float* __restrict__ dst, int R, int C)
{
    int idx = blockIdx.x*blockDim.x + threadIdx.x;
    if (idx >= R*C) return;
    int r = idx % R, c = idx / R;
    dst[idx] = src[(size_t)r*C + c];
}

// ---------------------------------------------------------------------------
// LSTM: xg0 = seq @ wih0T^T + (bih0+bhh0)
// ---------------------------------------------------------------------------
__global__ __launch_bounds__(512)
void xgates_kernel(const float* __restrict__ seq, const float* __restrict__ wT,
                   const float* __restrict__ bih, const float* __restrict__ bhh,
                   float* __restrict__ xg)
{
    __shared__ float xs[16*490];
    const int rt = blockIdx.x >> 3, jt_tile = blockIdx.x & 7;
    const int r0 = rt*16, jc = jt_tile*128;
    const int tid = threadIdx.x;
    for (int i = tid; i < 16*490; i += 512)
        xs[i] = seq[(size_t)(r0 + i/490)*490 + (i - (i/490)*490)];
    __syncthreads();
    const int bl = tid >> 5, jq = tid & 31;
    const int j = jc + jq*4;
    const float* xrow = &xs[bl*490];
    float4 acc;
    {
        float4 b1v = *(const float4*)&bih[j];
        float4 b2v = *(const float4*)&bhh[j];
        acc.x = b1v.x+b2v.x; acc.y = b1v.y+b2v.y; acc.z = b1v.z+b2v.z; acc.w = b1v.w+b2v.w;
    }
    const float* wp = wT + j;
    #pragma unroll 5
    for (int k = 0; k < 490; k++){
        float xv = xrow[k];
        float4 w = *(const float4*)&wp[(size_t)k*GATES];
        acc.x += w.x*xv; acc.y += w.y*xv; acc.z += w.z*xv; acc.w += w.w*xv;
    }
    *(float4*)&xg[(size_t)(r0 + bl)*GATES + j] = acc;
}

// fused launch L: blocks 0..31 do layer-0 step t=L (if L<5);
//                 blocks 32..63 do layer-1 step t=L-1 (if L>=1).
__global__ __launch_bounds__(512)
void lstm_fused(int L,
                const float* __restrict__ xg0, const float* __restrict__ whh0T,
                const float* __restrict__ wih1T, const float* __restrict__ whh1T,
                const float* __restrict__ bih1, const float* __restrict__ bhh1,
                float* __restrict__ h0a, float* __restrict__ h0b,
                float* __restrict__ h1a, float* __restrict__ h1b,
                float* __restrict__ cs0, float* __restrict__ cs1,
                float* __restrict__ out1, float* __restrict__ out2)
{
    __shared__ float smem[16*HID*2 + 4*16*32];
    const int tid = threadIdx.x;
    if (blockIdx.x < 32){
        if (L >= WIN) return;
        const int t = L;
        const float* hin  = (t & 1) ? h0b : h0a;
        float*       hout = (t & 1) ? h0a : h0b;
        float* xs = smem;                  // 16*HID
        float* lg = smem + 16*HID;         // 2048
        const int bt = blockIdx.x & 3, mt = blockIdx.x >> 2;
        const int b0 = bt*16, m0 = mt*32;
        for (int i = tid; i < 16*HID; i += 512)
            xs[i] = hin[(size_t)(b0 + (i>>8))*HID + (i&255)];
        __syncthreads();
        const int bl = tid >> 5, jq = tid & 31;
        const int g = jq >> 3, ms = (jq&7)*4;
        const int j = g*HID + m0 + ms;
        const float* xrow = &xs[bl*HID];
        float4 acc = *(const float4*)&xg0[((size_t)(b0+bl)*WIN + t)*GATES + j];
        const float* wp = whh0T + j;
        #pragma unroll 8
        for (int k = 0; k < HID; k++){
            float xv = xrow[k];
            float4 w = *(const float4*)&wp[(size_t)k*GATES];
            acc.x += w.x*xv; acc.y += w.y*xv; acc.z += w.z*xv; acc.w += w.w*xv;
        }
        *(float4*)&lg[(g*16 + bl)*32 + ms] = acc;
        __syncthreads();
        const int ib = tid >> 5, im = tid & 31;
        float gi = lg[(0*16+ib)*32+im], gf = lg[(1*16+ib)*32+im];
        float gg = lg[(2*16+ib)*32+im], go = lg[(3*16+ib)*32+im];
        const int gb = b0 + ib, gm = m0 + im;
        float c = cs0[(size_t)gb*HID + gm];
        c = sigm(gf)*c + sigm(gi)*tanhf(gg);
        float h = sigm(go)*tanhf(c);
        cs0[(size_t)gb*HID + gm] = c;
        hout[(size_t)gb*HID + gm] = h;
        out1[((size_t)gb*WIN + t)*HID + gm] = h;
    } else {
        if (L < 1) return;
        const int t = L - 1;
        const float* hin  = (t & 1) ? h1b : h1a;
        float*       hout = (t & 1) ? h1a : h1b;
        float* xs1 = smem;                 // 16*HID
        float* xs2 = smem + 16*HID;        // 16*HID
        float* lg  = smem + 2*16*HID;      // 2048
        const int blk = blockIdx.x - 32;
        const int bt = blk & 3, mt = blk >> 2;
        const int b0 = bt*16, m0 = mt*32;
        for (int i = tid; i < 16*HID; i += 512){
            xs1[i] = out1[((size_t)(b0 + (i>>8))*WIN + t)*HID + (i&255)];
            xs2[i] = hin[(size_t)(b0 + (i>>8))*HID + (i&255)];
        }
        __syncthreads();
        const int bl = tid >> 5, jq = tid & 31;
        const int g = jq >> 3, ms = (jq&7)*4;
        const int j = g*HID + m0 + ms;
        float4 acc;
        {
            float4 b1v = *(const float4*)&bih1[j];
            float4 b2v = *(const float4*)&bhh1[j];
            acc.x = b1v.x+b2v.x; acc.y = b1v.y+b2v.y; acc.z = b1v.z+b2v.z; acc.w = b1v.w+b2v.w;
        }
        const float* xrow1 = &xs1[bl*HID];
        const float* wp1 = wih1T + j;
        #pragma unroll 8
        for (int k = 0; k < HID; k++){
            float xv = xrow1[k];
            float4 w = *(const float4*)&wp1[(size_t)k*GATES];
            acc.x += w.x*xv; acc.y += w.y*xv; acc.z += w.z*xv; acc.w += w.w*xv;
        }
        const float* xrow2 = &xs2[bl*HID];
        const float* wp2 = whh1T + j;
        #pragma unroll 8
        for (int k = 0; k < HID; k++){
            float xv = xrow2[k];
            float4 w = *(const float4*)&wp2[(size_t)k*GATES];
            acc.x += w.x*xv; acc.y += w.y*xv; acc.z += w.z*xv; acc.w += w.w*xv;
        }
        *(float4*)&lg[(g*16 + bl)*32 + ms] = acc;
        __syncthreads();
        const int ib = tid >> 5, im = tid & 31;
        float gi = lg[(0*16+ib)*32+im], gf = lg[(1*16+ib)*32+im];
        float gg = lg[(2*16+ib)*32+im], go = lg[(3*16+ib)*32+im];
        const int gb = b0 + ib, gm = m0 + im;
        float c = cs1[(size_t)gb*HID + gm];
        c = sigm(gf)*c + sigm(gi)*tanhf(gg);
        float h = sigm(go)*tanhf(c);
        cs1[(size_t)gb*HID + gm] = c;
        hout[(size_t)gb*HID + gm] = h;
        out2[((size_t)gb*WIN + t)*HID + gm] = h;
    }
}

__global__ __launch_bounds__(256)
void attn_kernel(const float* __restrict__ out2, float* __restrict__ out)
{
    __shared__ float red[5*4];
    __shared__ float aw[5];
    const int b = blockIdx.x, tid = threadIdx.x;
    const float hl = out2[((size_t)b*WIN + 4)*HID + tid];
    const int wave = tid >> 6, lane = tid & 63;
    float v[5];
    #pragma unroll
    for (int t = 0; t < 5; t++){
        v[t] = out2[((size_t)b*WIN + t)*HID + tid];
        float p = v[t]*hl;
        for (int off = 32; off > 0; off >>= 1) p += __shfl_down(p, off);
        if (lane == 0) red[t*4 + wave] = p;
    }
    __syncthreads();
    if (tid == 0){
        float s[5], mx = -1e30f;
        for (int t = 0; t < 5; t++){ s[t] = red[t*4]+red[t*4+1]+red[t*4+2]+red[t*4+3]; mx = fmaxf(mx, s[t]); }
        float den = 0.f;
        for (int t = 0; t < 5; t++){ s[t] = expf(s[t]-mx); den += s[t]; }
        for (int t = 0; t < 5; t++) aw[t] = s[t]/den;
    }
    __syncthreads();
    float o = 0.f;
    #pragma unroll
    for (int t = 0; t < 5; t++) o += aw[t]*v[t];
    out[(size_t)b*HID + tid] = o;
}

extern "C" void kernel_launch(void* const* d_in, const int* in_sizes, int n_in,
                              void* d_out, int out_size, void* d_ws, size_t ws_size,
                              hipStream_t stream)
{
    const float* x     = (const float*)d_in[0];
    const float* w1    = (const float*)d_in[1];
    const float* g1    = (const float*)d_in[3];
    const float* be1   = (const float*)d_in[4];
    const float* w2    = (const float*)d_in[5];
    const float* g2    = (const float*)d_in[7];
    const float* be2   = (const float*)d_in[8];
    const float* w3    = (const float*)d_in[9];
    const float* g3    = (const float*)d_in[11];
    const float* be3   = (const float*)d_in[12];
    const float* w13   = (const float*)d_in[13];
    const float* g13   = (const float*)d_in[15];
    const float* be13  = (const float*)d_in[16];
    const float* gcn_w = (const float*)d_in[17];
    const float* edge_w= (const float*)d_in[19];
    const float* bn2g  = (const float*)d_in[20];
    const float* bn2b  = (const float*)d_in[21];
    const float* w11   = (const float*)d_in[22];
    const float* b11   = (const float*)d_in[23];
    const float* wih0  = (const float*)d_in[24];
    const float* whh0  = (const float*)d_in[25];
    const float* bih0  = (const float*)d_in[26];
    const float* bhh0  = (const float*)d_in[27];
    const float* wih1  = (const float*)d_in[28];
    const float* whh1  = (const float*)d_in[29];
    const float* bih1  = (const float*)d_in[30];
    const float* bhh1  = (const float*)d_in[31];
    const int*   ei    = (const int*)d_in[32];
    float* out = (float*)d_out;
    float* wsf = (float*)d_ws;
    (void)in_sizes; (void)n_in; (void)out_size; (void)ws_size;

    size_t off = 0;
    auto alloc = [&](size_t n){ size_t o = off; off += (n + 63) & ~(size_t)63; return o; };
    size_t Y13  = alloc((size_t)NB*C13*NCH*F150);    // 113 MB
    size_t FEAT = alloc((size_t)NN*WIN*F150);
    size_t HB   = alloc((size_t)NN*WIN*F100);
    size_t AGG  = alloc((size_t)NN*WIN*F100);        // [zeroed from here]
    size_t DEG  = alloc(NN);
    size_t ST13 = alloc(64*20);
    size_t BN2S = alloc(1000);
    size_t H0A  = alloc(Bb*HID);
    size_t H0B  = alloc(Bb*HID);
    size_t H1A  = alloc(Bb*HID);
    size_t H1B  = alloc(Bb*HID);
    size_t CS0  = alloc(Bb*HID);
    size_t CS1  = alloc(Bb*HID);
    size_t MB   = alloc(100*100);                    // Gram M
    size_t VB   = alloc(128);                        // column sums
    size_t SCLA = alloc(64);                         // [zero region ends here]
    size_t SFTA = alloc(64);
    size_t QB   = alloc(100*101);                    // diag prefixes (fully written)
    size_t RB   = alloc(128);
    size_t SC13 = alloc(16);
    size_t SF13 = alloc(16);
    size_t SCL2 = alloc(1024);
    size_t WT0I = alloc((size_t)490*1024);
    size_t WT0H = alloc((size_t)256*1024);
    size_t WT1I = alloc((size_t)256*1024);
    size_t WT1H = alloc((size_t)256*1024);
    size_t SEQ  = alloc((size_t)Bb*WIN*490);
    size_t XG0  = alloc((size_t)NB*GATES);
    size_t OUT1 = alloc((size_t)NB*HID);
    size_t OUT2 = alloc((size_t)NB*HID);

    float* y13   = wsf + Y13;
    float* feat  = wsf + FEAT;
    float* hbuf  = wsf + HB;
    float* agg   = wsf + AGG;
    float* dinv  = wsf + DEG;
    float* st13  = wsf + ST13;
    float* bn2s  = wsf + BN2S;
    float* h0a   = wsf + H0A;
    float* h0b   = wsf + H0B;
    float* h1a   = wsf + H1A;
    float* h1b   = wsf + H1B;
    float* cs0   = wsf + CS0;
    float* cs1   = wsf + CS1;
    float* Mbuf  = wsf + MB;
    float* Vbuf  = wsf + VB;
    float* sclA  = wsf + SCLA;
    float* sftA  = wsf + SFTA;
    float* Qbuf  = wsf + QB;
    float* Rbuf  = wsf + RB;
    float* sc13  = wsf + SC13;
    float* sf13  = wsf + SF13;
    float* scl2  = wsf + SCL2;
    float* wT0i  = wsf + WT0I;
    float* wT0h  = wsf + WT0H;
    float* wT1i  = wsf + WT1I;
    float* wT1h  = wsf + WT1H;
    float* seqb  = wsf + SEQ;
    float* xg0   = wsf + XG0;
    float* out1b = wsf + OUT1;
    float* out2b = wsf + OUT2;

    int nzero = (int)(SCLA - AGG);
    zero_kernel<<<(nzero+255)/256,256,0,stream>>>(wsf + AGG, nzero);

    {
        int n0 = 1024*490;
        transpose_kernel<<<(n0+255)/256,256,0,stream>>>(wih0, wT0i, 1024, 490);
        int n1 = 1024*256;
        transpose_kernel<<<(n1+255)/256,256,0,stream>>>(whh0, wT0h, 1024, 256);
        transpose_kernel<<<(n1+255)/256,256,0,stream>>>(wih1, wT1i, 1024, 256);
        transpose_kernel<<<(n1+255)/256,256,0,stream>>>(whh1, wT1h, 1024, 256);
    }

    // BN1 stats via Gram matrix (replaces the full stats conv pass)
    syrk_kernel<<<(NWIN+127)/128,256,0,stream>>>(x, Mbuf, Vbuf);
    qprep_kernel<<<1,128,0,stream>>>(Mbuf, Vbuf, Qbuf, Rbuf);
    gram_finalize<<<60,256,0,stream>>>(Qbuf, Rbuf, w1, w2, w3,
                                       g1, be1, g2, be2, g3, be3, sclA, sftA);

    // conv apply + mix
    conv1d_apply<125,62,0><<<NN,256,0,stream>>>(x, w1, sclA, sftA, w13, st13, y13);
    conv1d_apply< 59,29,1><<<NN,256,0,stream>>>(x, w2, sclA, sftA, w13, st13, y13);
    conv1d_apply< 31,15,2><<<NN,256,0,stream>>>(x, w3, sclA, sftA, w13, st13, y13);
    finalize_bn13<<<1,16,0,stream>>>(st13, g13, be13, sc13, sf13);

    feat_kernel<<<NROW,256,0,stream>>>(y13, sc13, sf13, feat);
    gcn_h_kernel<<<NROW/8,256,0,stream>>>(feat, gcn_w, hbuf);

    deg_kernel<<<(NE+255)/256,256,0,stream>>>(ei, edge_w, dinv);
    dinv_kernel<<<(NN+255)/256,256,0,stream>>>(dinv);
    agg_kernel<<<NE,64,0,stream>>>(ei, edge_w, dinv, hbuf, agg);
    bn2_stats_kernel<<<Bb,256,0,stream>>>(hbuf, dinv, agg, bn2s, bn2s+500);
    bn2_fin_kernel<<<2,256,0,stream>>>(bn2s, bn2s+500, bn2g, bn2b, scl2, scl2+500);

    zconv_kernel<<<NB,256,0,stream>>>(agg, scl2, scl2+500, w11, b11, seqb);

    // LSTM pipeline: xgates + 6 fused step launches + attention
    xgates_kernel<<<160,512,0,stream>>>(seqb, wT0i, bih0, bhh0, xg0);
    for (int L = 0; L <= WIN; L++){
        lstm_fused<<<64,512,0,stream>>>(L, xg0, wT0h, wT1i, wT1h, bih1, bhh1,
                                        h0a, h0b, h1a, h1b, cs0, cs1, out1b, out2b);
    }
    attn_kernel<<<Bb,256,0,stream>>>(out2b, out);
}

// Round 9
// 809.349 us; speedup vs baseline: 1.4332x; 1.0941x over previous
//
#include <hip/hip_runtime.h>
#include <math.h>

#define EPS 1e-5f

constexpr int NCH  = 59;
constexpr int T_   = 300;
constexpr int WIN  = 5;
constexpr int WSIZE= 100;
constexpr int Bb   = 64;
constexpr int NB   = Bb*WIN;     // 320
constexpr int NN   = Bb*NCH;     // 3776
constexpr int EW_N = 216;
constexpr int NE   = EW_N*Bb;    // 13824
constexpr int C1   = 20;
constexpr int C13  = 10;
constexpr int F150 = 150;
constexpr int F100 = 100;
constexpr int HID  = 256;
constexpr int GATES= 1024;
constexpr int NROW = NB*NCH;     // 18880
constexpr int NWIN = NROW;       // 18880 (row,win) windows
constexpr float CNT1  = 1888000.0f;   // NB*NCH*WSIZE
constexpr float CNT13 = 2832000.0f;   // NB*NCH*F150

__device__ __forceinline__ float leaky(float v){ return v >= 0.f ? v : 0.01f*v; }
__device__ __forceinline__ float sigm(float v){ return 1.f/(1.f+expf(-v)); }

__global__ __launch_bounds__(256)
void zero_kernel(float* __restrict__ p, int n)
{
    int i = blockIdx.x*256 + threadIdx.x;
    if (i < n) p[i] = 0.f;
}

// ---------------------------------------------------------------------------
// Gram-stats path (verified round 8): M = X^T X, V = col sums, Q/R prefixes,
// BN1 scale/shift from bilinear contraction.
// ---------------------------------------------------------------------------
__global__ __launch_bounds__(256)
void syrk_kernel(const float* __restrict__ x, float* __restrict__ M, float* __restrict__ V)
{
    __shared__ float xs[128*100 + 16];
    const int k0 = blockIdx.x * 128;
    const int tid = threadIdx.x;
    for (int i = tid; i < 128*100; i += 256){
        int wl = i / 100, u = i - wl*100;
        int w = k0 + wl;
        float v = 0.f;
        if (w < NWIN){
            int row = w / 5, win = w - row*5;
            v = x[(size_t)row*T_ + win*50 + u];
        }
        xs[i] = v;
    }
    if (tid < 16) xs[128*100 + tid] = 0.f;
    __syncthreads();
    if (tid < 100){
        float s = 0.f;
        for (int kk = 0; kk < 128; kk++) s += xs[kk*100 + tid];
        atomicAdd(&V[tid], s);
    }
    const int i = tid >> 4, j = tid & 15;
    float acc[7][7];
    #pragma unroll
    for (int a=0;a<7;a++)
        #pragma unroll
        for (int b=0;b<7;b++) acc[a][b]=0.f;
    for (int kk = 0; kk < 128; kk++){
        const float* xr = &xs[kk*100];
        float xu[7], xv[7];
        #pragma unroll
        for (int a=0;a<7;a++) xu[a] = xr[a*16 + i];
        #pragma unroll
        for (int b=0;b<7;b++) xv[b] = xr[b*16 + j];
        #pragma unroll
        for (int a=0;a<7;a++)
            #pragma unroll
            for (int b=0;b<7;b++) acc[a][b] += xu[a]*xv[b];
    }
    #pragma unroll
    for (int a=0;a<7;a++){
        int u = a*16 + i;
        if (u < 100){
            #pragma unroll
            for (int b=0;b<7;b++){
                int v = b*16 + j;
                if (v < 100) atomicAdd(&M[u*100 + v], acc[a][b]);
            }
        }
    }
}

__global__ void qprep_kernel(const float* __restrict__ M, const float* __restrict__ V,
                             float* __restrict__ Q, float* __restrict__ R)
{
    int d = threadIdx.x;
    if (d < 100){
        float s = 0.f;
        Q[d*101] = 0.f;
        for (int t = 1; t <= 100; t++){
            int u = t - 1;
            if (u + d < 100) s += M[u*100 + u + d];
            Q[d*101 + t] = s;
        }
    } else if (d == 100){
        float s = 0.f;
        R[0] = 0.f;
        for (int t = 1; t <= 100; t++){ s += V[t-1]; R[t] = s; }
    }
}

__global__ __launch_bounds__(256)
void gram_finalize(const float* __restrict__ Q, const float* __restrict__ Rg,
                   const float* __restrict__ w1, const float* __restrict__ w2, const float* __restrict__ w3,
                   const float* __restrict__ g1, const float* __restrict__ be1,
                   const float* __restrict__ g2, const float* __restrict__ be2,
                   const float* __restrict__ g3, const float* __restrict__ be3,
                   float* __restrict__ sclall, float* __restrict__ sftall)
{
    __shared__ float Qs[100*101];
    __shared__ float ws[128];
    __shared__ float Rs[104];
    __shared__ float red[8];
    const int conv = blockIdx.x / 20, c = blockIdx.x - conv*20;
    const int KW  = conv==0 ? 125 : (conv==1 ? 59 : 31);
    const int PAD = (KW-1)/2;
    const float* wt = conv==0 ? w1 : (conv==1 ? w2 : w3);
    const int tid = threadIdx.x;
    for (int i = tid; i < 100*101; i += 256) Qs[i] = Q[i];
    for (int i = tid; i < KW; i += 256) ws[i] = wt[c*KW + i];
    if (tid < 101) Rs[tid] = Rg[tid];
    __syncthreads();
    const int DMAX = KW < 100 ? KW : 100;
    float sq = 0.f;
    for (int d = 0; d < DMAX; d++){
        float fac = (d == 0) ? 1.f : 2.f;
        for (int k1 = tid; k1 < KW - d; k1 += 256){
            int lo = k1 - PAD; if (lo < 0) lo = 0;
            int hi = 100 - d; int h2 = 100 + k1 - PAD; if (h2 < hi) hi = h2;
            if (hi > lo) sq += fac * ws[k1]*ws[k1+d] * (Qs[d*101 + hi] - Qs[d*101 + lo]);
        }
    }
    float sm = 0.f;
    for (int k = tid; k < KW; k += 256){
        int lo = k - PAD; if (lo < 0) lo = 0;
        int hi = 100; int h2 = k - PAD + 100; if (h2 < hi) hi = h2;
        if (hi > lo) sm += ws[k]*(Rs[hi] - Rs[lo]);
    }
    for (int off = 32; off; off >>= 1){
        sq += __shfl_down(sq, off, 64);
        sm += __shfl_down(sm, off, 64);
    }
    int wave = tid >> 6, lane = tid & 63;
    if (lane == 0){ red[wave] = sq; red[4+wave] = sm; }
    __syncthreads();
    if (tid == 0){
        float q = (red[0]+red[1]+red[2]+red[3]) / CNT1;
        float m = (red[4]+red[5]+red[6]+red[7]) / CNT1;
        float var = q - m*m;
        float rs = rsqrtf(var + EPS);
        const float* g  = conv==0 ? g1  : (conv==1 ? g2  : g3);
        const float* be = conv==0 ? be1 : (conv==1 ? be2 : be3);
        sclall[conv*C1 + c] = rs*g[c];
        sftall[conv*C1 + c] = be[c] - m*rs*g[c];
    }
}

// ---------------------------------------------------------------------------
// Conv apply, 4 positions/thread: 2 rows per block, halves of 128 threads.
// thread = (win, q): conv positions 4q..4q+3 -> 2 pooled outputs.
// Per 4 taps: 1 ds_read_b128 + 20 s_load + 320 FMA (4 FMA per s_load).
// ---------------------------------------------------------------------------
template<int KW, int PAD, int CIDX>
__global__ __launch_bounds__(256)
void conv1d_apply4(const float* __restrict__ x, const float* __restrict__ wt_g,
                   const float* __restrict__ sclall, const float* __restrict__ sftall,
                   const float* __restrict__ w13,
                   float* __restrict__ stats13, float* __restrict__ y13)
{
    __shared__ float xp[2*WIN*240];
    __shared__ float lstat[2][2*C13];

    const int row0 = blockIdx.x*2;
    const int tid = threadIdx.x;
    const int half = tid >> 7;
    const int t2 = tid & 127;
    const int row = row0 + half;
    const int b = row / NCH, hh = row - b*NCH;

    for (int i = tid; i < 2*WIN*240; i += 256){
        int rr = i / 1200, ii = i - rr*1200;
        int win = ii/240, jj = ii - win*240;
        int t = jj - PAD;
        xp[i] = (t >= 0 && t < WSIZE) ? x[(size_t)(row0+rr)*T_ + win*50 + t] : 0.f;
    }
    if (t2 < 2*C13) lstat[half][t2] = 0.f;
    __syncthreads();

    const bool active = (t2 < 125);
    const int win = t2/25, q = t2 - win*25;

    float a[C1][4];
    #pragma unroll
    for (int c = 0; c < C1; c++){ a[c][0]=0.f; a[c][1]=0.f; a[c][2]=0.f; a[c][3]=0.f; }

    if (active){
        const float* xw = &xp[half*1200 + win*240 + 4*q];
        float xv[8];
        #pragma unroll
        for (int i = 0; i < 4; i++) xv[i] = xw[i];
        constexpr int KB = KW/4;
        for (int kb = 0; kb < KB; kb++){
            float4 nx = *(const float4*)&xw[kb*4 + 4];   // 16B-aligned slide
            xv[4]=nx.x; xv[5]=nx.y; xv[6]=nx.z; xv[7]=nx.w;
            #pragma unroll
            for (int j = 0; j < 4; j++){
                const int k = kb*4 + j;
                #pragma unroll
                for (int c = 0; c < C1; c++){
                    float wv = wt_g[c*KW + k];           // wave-uniform -> s_load
                    a[c][0] += wv*xv[j];
                    a[c][1] += wv*xv[j+1];
                    a[c][2] += wv*xv[j+2];
                    a[c][3] += wv*xv[j+3];
                }
            }
            xv[0]=xv[4]; xv[1]=xv[5]; xv[2]=xv[6]; xv[3]=xv[7];
        }
        constexpr int KT = KW - KB*4;
        if (KT > 0){
            float4 nx = *(const float4*)&xw[KB*4 + 4];
            xv[4]=nx.x; xv[5]=nx.y; xv[6]=nx.z; xv[7]=nx.w;
            #pragma unroll
            for (int jt = 0; jt < KT; jt++){
                const int k = KB*4 + jt;
                #pragma unroll
                for (int c = 0; c < C1; c++){
                    float wv = wt_g[c*KW + k];
                    a[c][0] += wv*xv[jt];
                    a[c][1] += wv*xv[jt+1];
                    a[c][2] += wv*xv[jt+2];
                    a[c][3] += wv*xv[jt+3];
                }
            }
        }
    }

    float y[C13][2];
    if (active){
        float pooled[C1][2];
        #pragma unroll
        for (int c = 0; c < C1; c++){
            float sc = sclall[CIDX*C1 + c];
            float sf = sftall[CIDX*C1 + c];
            pooled[c][0] = 0.5f*(leaky(a[c][0]*sc + sf) + leaky(a[c][1]*sc + sf));
            pooled[c][1] = 0.5f*(leaky(a[c][2]*sc + sf) + leaky(a[c][3]*sc + sf));
        }
        #pragma unroll
        for (int o = 0; o < C13; o++){
            float acc0 = 0.f, acc1 = 0.f;
            #pragma unroll
            for (int c = 0; c < C1; c++){
                float wv = w13[o*C1 + c];
                acc0 += wv*pooled[c][0];
                acc1 += wv*pooled[c][1];
            }
            y[o][0] = acc0; y[o][1] = acc1;      // b13 cancels in BN13
        }
        const int n = b*WIN + win;
        #pragma unroll
        for (int o = 0; o < C13; o++){
            float2 st2 = make_float2(y[o][0], y[o][1]);
            *(float2*)&y13[(((size_t)n*C13 + o)*NCH + hh)*F150 + CIDX*50 + 2*q] = st2;
        }
    } else {
        #pragma unroll
        for (int o = 0; o < C13; o++){ y[o][0]=0.f; y[o][1]=0.f; }
    }
    #pragma unroll
    for (int o = 0; o < C13; o++){
        float s = y[o][0] + y[o][1];
        float qq = y[o][0]*y[o][0] + y[o][1]*y[o][1];
        for (int off = 32; off; off >>= 1){
            s  += __shfl_down(s,  off, 64);
            qq += __shfl_down(qq, off, 64);
        }
        if ((tid & 63) == 0){
            atomicAdd(&lstat[half][o],       s);
            atomicAdd(&lstat[half][C13 + o], qq);
        }
    }
    __syncthreads();
    if (t2 < 2*C13) atomicAdd(&stats13[(row & 63)*(2*C13) + t2], lstat[half][t2]);
}

__global__ void finalize_bn13(const float* __restrict__ stats13,
                              const float* __restrict__ g13, const float* __restrict__ be13,
                              float* __restrict__ scl13, float* __restrict__ sft13)
{
    int o = threadIdx.x;
    if (o >= C13) return;
    float s=0.f, q=0.f;
    for (int st=0; st<64; st++){
        s += stats13[st*20 + o];
        q += stats13[st*20 + C13 + o];
    }
    float m = s/CNT13, v = q/CNT13 - m*m;
    float rs = rsqrtf(v + EPS);
    scl13[o] = rs*g13[o];
    sft13[o] = be13[o] - m*rs*g13[o];
}

// -------- fused: BN13 + leaky + channel-sum + (150x100) matmul -> h ------------------------
__global__ __launch_bounds__(256)
void feat_gcn_kernel(const float* __restrict__ y13,
                     const float* __restrict__ scl13, const float* __restrict__ sft13,
                     const float* __restrict__ gw,
                     float* __restrict__ h)
{
    __shared__ float fr[8*F150];
    __shared__ float scl[C13], sft[C13];
    const int r0 = blockIdx.x*8;
    const int tid = threadIdx.x;
    if (tid < C13){ scl[tid] = scl13[tid]; sft[tid] = sft13[tid]; }
    __syncthreads();
    for (int i = tid; i < 8*F150; i += 256){
        int rr = i/F150, f = i - rr*F150;
        int r = r0 + rr;
        int bq = r/(NCH*WIN), rem = r - bq*(NCH*WIN);
        int hh = rem/WIN, win = rem - hh*WIN;
        int n = bq*WIN + win;
        float acc = 0.f;
        #pragma unroll
        for (int o = 0; o < C13; o++){
            float v = y13[(((size_t)n*C13 + o)*NCH + hh)*F150 + f];
            acc += leaky(v*scl[o] + sft[o]);
        }
        fr[i] = acc;
    }
    __syncthreads();
    for (int idx = tid; idx < 8*F100; idx += 256){
        int rr = idx / F100, j = idx - rr*F100;
        float acc = 0.f;
        const float* f = &fr[rr*F150];
        for (int k = 0; k < F150; k++) acc += f[k]*gw[k*F100 + j];
        h[(size_t)(r0+rr)*F100 + j] = acc;
    }
}

__global__ void deg_kernel(const int* __restrict__ ei, const float* __restrict__ ew,
                           float* __restrict__ deg)
{
    int e = blockIdx.x*blockDim.x + threadIdx.x;
    if (e >= NE) return;
    int c = ei[NE + e];
    float w = ew[e % EW_N]; w = w > 0.f ? w : 0.f;
    atomicAdd(&deg[c], w);
}

__global__ void dinv_kernel(float* __restrict__ deg)
{
    int i = blockIdx.x*blockDim.x + threadIdx.x;
    if (i < NN) deg[i] = rsqrtf(deg[i] + 1.0f);
}

__global__ __launch_bounds__(64)
void agg_kernel(const int* __restrict__ ei, const float* __restrict__ ew,
                const float* __restrict__ dinv, const float* __restrict__ h,
                float* __restrict__ agg)
{
    int e = blockIdx.x;
    int r = ei[e], c = ei[NE + e];
    float w = ew[e % EW_N]; w = w > 0.f ? w : 0.f;
    float nrm = dinv[r]*w*dinv[c];
    const float* hr = h + (size_t)r*(WIN*F100);
    float* ac = agg + (size_t)c*(WIN*F100);
    for (int i = threadIdx.x; i < WIN*F100; i += 64)
        atomicAdd(&ac[i], hr[i]*nrm);
}

// grid 236, 16 nodes per block (was 64 x 59 -> quarter of the machine)
__global__ __launch_bounds__(256)
void bn2_stats_kernel(const float* __restrict__ h, const float* __restrict__ dinv,
                      float* __restrict__ agg, float* __restrict__ s2sum, float* __restrict__ s2sq)
{
    int tid = threadIdx.x;
    int c0 = tid, c1 = tid + 256;
    float s0=0.f,q0=0.f,s1=0.f,q1=0.f;
    for (int rr = 0; rr < 16; rr++){
        int node = blockIdx.x*16 + rr;
        float d = dinv[node]; float d2 = d*d;
        const float* hr = h + (size_t)node*(WIN*F100);
        float* ar = agg + (size_t)node*(WIN*F100);
        float v0 = ar[c0] + hr[c0]*d2;
        ar[c0] = v0; s0 += v0; q0 += v0*v0;
        if (c1 < WIN*F100){
            float v1 = ar[c1] + hr[c1]*d2;
            ar[c1] = v1; s1 += v1; q1 += v1*v1;
        }
    }
    atomicAdd(&s2sum[c0], s0); atomicAdd(&s2sq[c0], q0);
    if (c1 < WIN*F100){ atomicAdd(&s2sum[c1], s1); atomicAdd(&s2sq[c1], q1); }
}

__global__ void bn2_fin_kernel(const float* __restrict__ s2sum, const float* __restrict__ s2sq,
                               const float* __restrict__ g2, const float* __restrict__ b2,
                               float* __restrict__ scl2, float* __restrict__ sft2)
{
    int c = blockIdx.x*blockDim.x + threadIdx.x;
    if (c >= WIN*F100) return;
    int f = c % F100;
    float m = s2sum[c]/(float)NN;
    float v = s2sq[c]/(float)NN - m*m;
    float rs = rsqrtf(v + EPS);
    scl2[c] = rs*g2[f];
    sft2[c] = b2[f] - m*rs*g2[f];
}

__global__ __launch_bounds__(256)
void zconv_kernel(const float* __restrict__ agg,
                  const float* __restrict__ scl2, const float* __restrict__ sft2,
                  const float* __restrict__ w11, const float* __restrict__ b11,
                  float* __restrict__ seq)
{
    __shared__ float z[NCH*WSIZE];
    __shared__ float ws[C13*NCH*2];
    __shared__ float sc[WSIZE], sf[WSIZE];
    int n = blockIdx.x;
    int b = n / WIN, win = n - b*WIN;
    int tid = threadIdx.x;
    if (tid < WSIZE){ sc[tid] = scl2[win*F100 + tid]; sf[tid] = sft2[win*F100 + tid]; }
    for (int i = tid; i < C13*NCH*2; i += 256) ws[i] = w11[i];
    __syncthreads();
    for (int i = tid; i < NCH*WSIZE; i += 256){
        int ch = i / WSIZE, t = i - ch*WSIZE;
        int node = b*NCH + ch;
        float v = agg[(size_t)node*(WIN*F100) + win*F100 + t];
        z[i] = v*sc[t] + sf[t];
    }
    __syncthreads();
    float* sq = seq + (size_t)n*490;
    for (int idx = tid; idx < C13*49; idx += 256){
        int o = idx / 49, p = idx - o*49;
        float ve = b11[o], vo = b11[o];
        const float* wo = &ws[o*NCH*2];
        for (int ch = 0; ch < NCH; ch++){
            float z0 = z[ch*WSIZE + 2*p];
            float z1 = z[ch*WSIZE + 2*p + 1];
            float z2 = z[ch*WSIZE + 2*p + 2];
            float w0 = wo[ch*2], w1 = wo[ch*2 + 1];
            ve += w0*z0 + w1*z1;
            vo += w0*z1 + w1*z2;
        }
        sq[o*49 + p] = 0.5f*(leaky(ve) + leaky(vo));
    }
}

__global__ void transpose_kernel(const float* __restrict__ src, float* __restrict__ dst, int R, int C)
{
    int idx = blockIdx.x*blockDim.x + threadIdx.x;
    if (idx >= R*C) return;
    int r = idx % R, c = idx / R;
    dst[idx] = src[(size_t)r*C + c];
}

// ---------------------------------------------------------------------------
// LSTM: xg0 = seq @ wih0T^T + (bih0+bhh0)
// ---------------------------------------------------------------------------
__global__ __launch_bounds__(512)
void xgates_kernel(const float* __restrict__ seq, const float* __restrict__ wT,
                   const float* __restrict__ bih, const float* __restrict__ bhh,
                   float* __restrict__ xg)
{
    __shared__ float xs[16*490];
    const int rt = blockIdx.x >> 3, jt_tile = blockIdx.x & 7;
    const int r0 = rt*16, jc = jt_tile*128;
    const int tid = threadIdx.x;
    for (int i = tid; i < 16*490; i += 512)
        xs[i] = seq[(size_t)(r0 + i/490)*490 + (i - (i/490)*490)];
    __syncthreads();
    const int bl = tid >> 5, jq = tid & 31;
    const int j = jc + jq*4;
    const float* xrow = &xs[bl*490];
    float4 acc;
    {
        float4 b1v = *(const float4*)&bih[j];
        float4 b2v = *(const float4*)&bhh[j];
        acc.x = b1v.x+b2v.x; acc.y = b1v.y+b2v.y; acc.z = b1v.z+b2v.z; acc.w = b1v.w+b2v.w;
    }
    const float* wp = wT + j;
    #pragma unroll 5
    for (int k = 0; k < 490; k++){
        float xv = xrow[k];
        float4 w = *(const float4*)&wp[(size_t)k*GATES];
        acc.x += w.x*xv; acc.y += w.y*xv; acc.z += w.z*xv; acc.w += w.w*xv;
    }
    *(float4*)&xg[(size_t)(r0 + bl)*GATES + j] = acc;
}

// fused launch L: blocks 0..31 layer-0 step t=L (L<5); blocks 32..63 layer-1 step t=L-1 (L>=1)
__global__ __launch_bounds__(512)
void lstm_fused(int L,
                const float* __restrict__ xg0, const float* __restrict__ whh0T,
                const float* __restrict__ wih1T, const float* __restrict__ whh1T,
                const float* __restrict__ bih1, const float* __restrict__ bhh1,
                float* __restrict__ h0a, float* __restrict__ h0b,
                float* __restrict__ h1a, float* __restrict__ h1b,
                float* __restrict__ cs0, float* __restrict__ cs1,
                float* __restrict__ out1, float* __restrict__ out2)
{
    __shared__ float smem[16*HID*2 + 4*16*32];
    const int tid = threadIdx.x;
    if (blockIdx.x < 32){
        if (L >= WIN) return;
        const int t = L;
        const float* hin  = (t & 1) ? h0b : h0a;
        float*       hout = (t & 1) ? h0a : h0b;
        float* xs = smem;
        float* lg = smem + 16*HID;
        const int bt = blockIdx.x & 3, mt = blockIdx.x >> 2;
        const int b0 = bt*16, m0 = mt*32;
        for (int i = tid; i < 16*HID; i += 512)
            xs[i] = hin[(size_t)(b0 + (i>>8))*HID + (i&255)];
        __syncthreads();
        const int bl = tid >> 5, jq = tid & 31;
        const int g = jq >> 3, ms = (jq&7)*4;
        const int j = g*HID + m0 + ms;
        const float* xrow = &xs[bl*HID];
        float4 acc = *(const float4*)&xg0[((size_t)(b0+bl)*WIN + t)*GATES + j];
        const float* wp = whh0T + j;
        #pragma unroll 8
        for (int k = 0; k < HID; k++){
            float xv = xrow[k];
            float4 w = *(const float4*)&wp[(size_t)k*GATES];
            acc.x += w.x*xv; acc.y += w.y*xv; acc.z += w.z*xv; acc.w += w.w*xv;
        }
        *(float4*)&lg[(g*16 + bl)*32 + ms] = acc;
        __syncthreads();
        const int ib = tid >> 5, im = tid & 31;
        float gi = lg[(0*16+ib)*32+im], gf = lg[(1*16+ib)*32+im];
        float gg = lg[(2*16+ib)*32+im], go = lg[(3*16+ib)*32+im];
        const int gb = b0 + ib, gm = m0 + im;
        float c = cs0[(size_t)gb*HID + gm];
        c = sigm(gf)*c + sigm(gi)*tanhf(gg);
        float h = sigm(go)*tanhf(c);
        cs0[(size_t)gb*HID + gm] = c;
        hout[(size_t)gb*HID + gm] = h;
        out1[((size_t)gb*WIN + t)*HID + gm] = h;
    } else {
        if (L < 1) return;
        const int t = L - 1;
        const float* hin  = (t & 1) ? h1b : h1a;
        float*       hout = (t & 1) ? h1a : h1b;
        float* xs1 = smem;
        float* xs2 = smem + 16*HID;
        float* lg  = smem + 2*16*HID;
        const int blk = blockIdx.x - 32;
        const int bt = blk & 3, mt = blk >> 2;
        const int b0 = bt*16, m0 = mt*32;
        for (int i = tid; i < 16*HID; i += 512){
            xs1[i] = out1[((size_t)(b0 + (i>>8))*WIN + t)*HID + (i&255)];
            xs2[i] = hin[(size_t)(b0 + (i>>8))*HID + (i&255)];
        }
        __syncthreads();
        const int bl = tid >> 5, jq = tid & 31;
        const int g = jq >> 3, ms = (jq&7)*4;
        const int j = g*HID + m0 + ms;
        float4 acc;
        {
            float4 b1v = *(const float4*)&bih1[j];
            float4 b2v = *(const float4*)&bhh1[j];
            acc.x = b1v.x+b2v.x; acc.y = b1v.y+b2v.y; acc.z = b1v.z+b2v.z; acc.w = b1v.w+b2v.w;
        }
        const float* xrow1 = &xs1[bl*HID];
        const float* wp1 = wih1T + j;
        #pragma unroll 8
        for (int k = 0; k < HID; k++){
            float xv = xrow1[k];
            float4 w = *(const float4*)&wp1[(size_t)k*GATES];
            acc.x += w.x*xv; acc.y += w.y*xv; acc.z += w.z*xv; acc.w += w.w*xv;
        }
        const float* xrow2 = &xs2[bl*HID];
        const float* wp2 = whh1T + j;
        #pragma unroll 8
        for (int k = 0; k < HID; k++){
            float xv = xrow2[k];
            float4 w = *(const float4*)&wp2[(size_t)k*GATES];
            acc.x += w.x*xv; acc.y += w.y*xv; acc.z += w.z*xv; acc.w += w.w*xv;
        }
        *(float4*)&lg[(g*16 + bl)*32 + ms] = acc;
        __syncthreads();
        const int ib = tid >> 5, im = tid & 31;
        float gi = lg[(0*16+ib)*32+im], gf = lg[(1*16+ib)*32+im];
        float gg = lg[(2*16+ib)*32+im], go = lg[(3*16+ib)*32+im];
        const int gb = b0 + ib, gm = m0 + im;
        float c = cs1[(size_t)gb*HID + gm];
        c = sigm(gf)*c + sigm(gi)*tanhf(gg);
        float h = sigm(go)*tanhf(c);
        cs1[(size_t)gb*HID + gm] = c;
        hout[(size_t)gb*HID + gm] = h;
        out2[((size_t)gb*WIN + t)*HID + gm] = h;
    }
}

__global__ __launch_bounds__(256)
void attn_kernel(const float* __restrict__ out2, float* __restrict__ out)
{
    __shared__ float red[5*4];
    __shared__ float aw[5];
    const int b = blockIdx.x, tid = threadIdx.x;
    const float hl = out2[((size_t)b*WIN + 4)*HID + tid];
    const int wave = tid >> 6, lane = tid & 63;
    float v[5];
    #pragma unroll
    for (int t = 0; t < 5; t++){
        v[t] = out2[((size_t)b*WIN + t)*HID + tid];
        float p = v[t]*hl;
        for (int off = 32; off > 0; off >>= 1) p += __shfl_down(p, off);
        if (lane == 0) red[t*4 + wave] = p;
    }
    __syncthreads();
    if (tid == 0){
        float s[5], mx = -1e30f;
        for (int t = 0; t < 5; t++){ s[t] = red[t*4]+red[t*4+1]+red[t*4+2]+red[t*4+3]; mx = fmaxf(mx, s[t]); }
        float den = 0.f;
        for (int t = 0; t < 5; t++){ s[t] = expf(s[t]-mx); den += s[t]; }
        for (int t = 0; t < 5; t++) aw[t] = s[t]/den;
    }
    __syncthreads();
    float o = 0.f;
    #pragma unroll
    for (int t = 0; t < 5; t++) o += aw[t]*v[t];
    out[(size_t)b*HID + tid] = o;
}

extern "C" void kernel_launch(void* const* d_in, const int* in_sizes, int n_in,
                              void* d_out, int out_size, void* d_ws, size_t ws_size,
                              hipStream_t stream)
{
    const float* x     = (const float*)d_in[0];
    const float* w1    = (const float*)d_in[1];
    const float* g1    = (const float*)d_in[3];
    const float* be1   = (const float*)d_in[4];
    const float* w2    = (const float*)d_in[5];
    const float* g2    = (const float*)d_in[7];
    const float* be2   = (const float*)d_in[8];
    const float* w3    = (const float*)d_in[9];
    const float* g3    = (const float*)d_in[11];
    const float* be3   = (const float*)d_in[12];
    const float* w13   = (const float*)d_in[13];
    const float* g13   = (const float*)d_in[15];
    const float* be13  = (const float*)d_in[16];
    const float* gcn_w = (const float*)d_in[17];
    const float* edge_w= (const float*)d_in[19];
    const float* bn2g  = (const float*)d_in[20];
    const float* bn2b  = (const float*)d_in[21];
    const float* w11   = (const float*)d_in[22];
    const float* b11   = (const float*)d_in[23];
    const float* wih0  = (const float*)d_in[24];
    const float* whh0  = (const float*)d_in[25];
    const float* bih0  = (const float*)d_in[26];
    const float* bhh0  = (const float*)d_in[27];
    const float* wih1  = (const float*)d_in[28];
    const float* whh1  = (const float*)d_in[29];
    const float* bih1  = (const float*)d_in[30];
    const float* bhh1  = (const float*)d_in[31];
    const int*   ei    = (const int*)d_in[32];
    float* out = (float*)d_out;
    float* wsf = (float*)d_ws;
    (void)in_sizes; (void)n_in; (void)out_size; (void)ws_size;

    size_t off = 0;
    auto alloc = [&](size_t n){ size_t o = off; off += (n + 63) & ~(size_t)63; return o; };
    size_t Y13  = alloc((size_t)NB*C13*NCH*F150);    // 113 MB
    size_t HB   = alloc((size_t)NN*WIN*F100);
    size_t AGG  = alloc((size_t)NN*WIN*F100);        // [zeroed from here]
    size_t DEG  = alloc(NN);
    size_t ST13 = alloc(64*20);
    size_t BN2S = alloc(1000);
    size_t H0A  = alloc(Bb*HID);
    size_t H0B  = alloc(Bb*HID);
    size_t H1A  = alloc(Bb*HID);
    size_t H1B  = alloc(Bb*HID);
    size_t CS0  = alloc(Bb*HID);
    size_t CS1  = alloc(Bb*HID);
    size_t MB   = alloc(100*100);                    // Gram M
    size_t VB   = alloc(128);                        // column sums
    size_t SCLA = alloc(64);                         // [zero region ends here]
    size_t SFTA = alloc(64);
    size_t QB   = alloc(100*101);
    size_t RB   = alloc(128);
    size_t SC13 = alloc(16);
    size_t SF13 = alloc(16);
    size_t SCL2 = alloc(1024);
    size_t WT0I = alloc((size_t)490*1024);
    size_t WT0H = alloc((size_t)256*1024);
    size_t WT1I = alloc((size_t)256*1024);
    size_t WT1H = alloc((size_t)256*1024);
    size_t SEQ  = alloc((size_t)Bb*WIN*490);
    size_t XG0  = alloc((size_t)NB*GATES);
    size_t OUT1 = alloc((size_t)NB*HID);
    size_t OUT2 = alloc((size_t)NB*HID);

    float* y13   = wsf + Y13;
    float* hbuf  = wsf + HB;
    float* agg   = wsf + AGG;
    float* dinv  = wsf + DEG;
    float* st13  = wsf + ST13;
    float* bn2s  = wsf + BN2S;
    float* h0a   = wsf + H0A;
    float* h0b   = wsf + H0B;
    float* h1a   = wsf + H1A;
    float* h1b   = wsf + H1B;
    float* cs0   = wsf + CS0;
    float* cs1   = wsf + CS1;
    float* Mbuf  = wsf + MB;
    float* Vbuf  = wsf + VB;
    float* sclA  = wsf + SCLA;
    float* sftA  = wsf + SFTA;
    float* Qbuf  = wsf + QB;
    float* Rbuf  = wsf + RB;
    float* sc13  = wsf + SC13;
    float* sf13  = wsf + SF13;
    float* scl2  = wsf + SCL2;
    float* wT0i  = wsf + WT0I;
    float* wT0h  = wsf + WT0H;
    float* wT1i  = wsf + WT1I;
    float* wT1h  = wsf + WT1H;
    float* seqb  = wsf + SEQ;
    float* xg0   = wsf + XG0;
    float* out1b = wsf + OUT1;
    float* out2b = wsf + OUT2;

    int nzero = (int)(SCLA - AGG);
    zero_kernel<<<(nzero+255)/256,256,0,stream>>>(wsf + AGG, nzero);

    {
        int n0 = 1024*490;
        transpose_kernel<<<(n0+255)/256,256,0,stream>>>(wih0, wT0i, 1024, 490);
        int n1 = 1024*256;
        transpose_kernel<<<(n1+255)/256,256,0,stream>>>(whh0, wT0h, 1024, 256);
        transpose_kernel<<<(n1+255)/256,256,0,stream>>>(wih1, wT1i, 1024, 256);
        transpose_kernel<<<(n1+255)/256,256,0,stream>>>(whh1, wT1h, 1024, 256);
    }

    // BN1 stats via Gram matrix
    syrk_kernel<<<(NWIN+127)/128,256,0,stream>>>(x, Mbuf, Vbuf);
    qprep_kernel<<<1,128,0,stream>>>(Mbuf, Vbuf, Qbuf, Rbuf);
    gram_finalize<<<60,256,0,stream>>>(Qbuf, Rbuf, w1, w2, w3,
                                       g1, be1, g2, be2, g3, be3, sclA, sftA);

    // conv apply + mix (2 rows per block, 4 positions per thread)
    conv1d_apply4<125,62,0><<<NN/2,256,0,stream>>>(x, w1, sclA, sftA, w13, st13, y13);
    conv1d_apply4< 59,29,1><<<NN/2,256,0,stream>>>(x, w2, sclA, sftA, w13, st13, y13);
    conv1d_apply4< 31,15,2><<<NN/2,256,0,stream>>>(x, w3, sclA, sftA, w13, st13, y13);
    finalize_bn13<<<1,16,0,stream>>>(st13, g13, be13, sc13, sf13);

    feat_gcn_kernel<<<NROW/8,256,0,stream>>>(y13, sc13, sf13, gcn_w, hbuf);

    deg_kernel<<<(NE+255)/256,256,0,stream>>>(ei, edge_w, dinv);
    dinv_kernel<<<(NN+255)/256,256,0,stream>>>(dinv);
    agg_kernel<<<NE,64,0,stream>>>(ei, edge_w, dinv, hbuf, agg);
    bn2_stats_kernel<<<NN/16,256,0,stream>>>(hbuf, dinv, agg, bn2s, bn2s+500);
    bn2_fin_kernel<<<2,256,0,stream>>>(bn2s, bn2s+500, bn2g, bn2b, scl2, scl2+500);

    zconv_kernel<<<NB,256,0,stream>>>(agg, scl2, scl2+500, w11, b11, seqb);

    // LSTM pipeline
    xgates_kernel<<<160,512,0,stream>>>(seqb, wT0i, bih0, bhh0, xg0);
    for (int L = 0; L <= WIN; L++){
        lstm_fused<<<64,512,0,stream>>>(L, xg0, wT0h, wT1i, wT1h, bih1, bhh1,
                                        h0a, h0b, h1a, h1b, cs0, cs1, out1b, out2b);
    }
    attn_kernel<<<Bb,256,0,stream>>>(out2b, out);
}